// Round 1
// baseline (1332.747 us; speedup 1.0000x reference)
//
#include <hip/hip_runtime.h>
#include <math.h>

static constexpr int BB = 64;      // batch
static constexpr int TT = 64;      // tgt seq len
static constexpr int VV = 32000;   // vocab
static constexpr int II = 512;     // embed dim
static constexpr int HH = 1024;    // hidden
static constexpr int GG = 2048;    // img dim
static constexpr int NT = 63;      // LSTM steps
static constexpr int NR = NT * BB; // 4032 output rows

using s16x8 = __attribute__((ext_vector_type(8))) short;
using f32x4 = __attribute__((ext_vector_type(4))) float;

__device__ __forceinline__ unsigned short f2bf(float f) {
    union { float f; unsigned u; } v; v.f = f;
    unsigned r = v.u + 0x7FFFu + ((v.u >> 16) & 1u);
    return (unsigned short)(r >> 16);
}

// ---------- f32 -> bf16 convert ----------
__global__ void cvt_kernel(const float* __restrict__ in,
                           unsigned short* __restrict__ out, int n4) {
    int idx = blockIdx.x * blockDim.x + threadIdx.x;
    int stride = gridDim.x * blockDim.x;
    for (int i = idx; i < n4; i += stride) {
        float4 v = ((const float4*)in)[i];
        ushort4 o;
        o.x = f2bf(v.x); o.y = f2bf(v.y); o.z = f2bf(v.z); o.w = f2bf(v.w);
        ((ushort4*)out)[i] = o;
    }
}

// ---------- embedding gather (+ target ids) ----------
__global__ void gather_kernel(const float* __restrict__ embed,
                              const int* __restrict__ tgt_ids,
                              unsigned short* __restrict__ X,
                              int* __restrict__ TGT) {
    int idx = blockIdx.x * 256 + threadIdx.x;   // over NR * II/4
    if (idx >= NR * (II / 4)) return;
    int r = idx / (II / 4);
    int kq = idx % (II / 4);
    int t = r / BB, b = r % BB;
    int tok = tgt_ids[b * TT + t];
    float4 v = ((const float4*)(embed + (size_t)tok * II))[kq];
    ushort4 o;
    o.x = f2bf(v.x); o.y = f2bf(v.y); o.z = f2bf(v.z); o.w = f2bf(v.w);
    ((ushort4*)(X + (size_t)r * II))[kq] = o;
    if (kq == 0) TGT[r] = tgt_ids[b * TT + t + 1];
}

// ---------- h0/c0 init: wave computes 8 batches for one j ----------
// waves = 2 * 1024 * 8 = 16384 (sel, j, b-group of 8)
__global__ __launch_bounds__(256) void init_hc_kernel(
    const float* __restrict__ src,
    const float* __restrict__ W_h, const float* __restrict__ b_h,
    const float* __restrict__ W_c, const float* __restrict__ b_c,
    unsigned short* __restrict__ HS, float* __restrict__ C) {
    int wave = blockIdx.x * 4 + (threadIdx.x >> 6);
    int lane = threadIdx.x & 63;
    int sel = wave >> 13;          // 0 = h, 1 = c
    int rem = wave & 8191;
    int j = rem >> 3;
    int b0 = (rem & 7) * 8;
    const float* w = (sel ? W_c : W_h) + (size_t)j * GG;
    float acc[8] = {0.f,0.f,0.f,0.f,0.f,0.f,0.f,0.f};
    for (int k = lane; k < GG; k += 64) {
        float wv = w[k];
#pragma unroll
        for (int bb = 0; bb < 8; ++bb)
            acc[bb] += wv * src[(size_t)(b0 + bb) * GG + k];
    }
#pragma unroll
    for (int bb = 0; bb < 8; ++bb)
        for (int off = 32; off; off >>= 1)
            acc[bb] += __shfl_xor(acc[bb], off);
    if (lane == 0) {
        float bias = sel ? b_c[j] : b_h[j];
#pragma unroll
        for (int bb = 0; bb < 8; ++bb) {
            float v = tanhf(acc[bb] + bias);
            if (sel == 0) HS[(size_t)(b0 + bb) * HH + j] = f2bf(v);
            else          C[(size_t)(b0 + bb) * HH + j] = v;
        }
    }
}

// ---------- fused LSTM step: [h_t | x_t] @ [W_hh | W_ih]^T + gates ----------
// grid 256 blocks: block handles 4 hidden units (16 cols = 4 gates x 4 units)
static constexpr int KC = 128;
static constexpr int KPAD = 136;   // +8 bf16 = +16 B pad
__global__ __launch_bounds__(256) void lstm_step_kernel(
    unsigned short* __restrict__ HS,          // [64 slots][64][1024]
    const unsigned short* __restrict__ X,     // [4032][512]
    const unsigned short* __restrict__ Whh,   // [4096][1024]
    const unsigned short* __restrict__ Wih,   // [4096][512]
    const float* __restrict__ b_ih, const float* __restrict__ b_hh,
    float* __restrict__ C, int t) {
    __shared__ unsigned short Al[64 * KPAD];
    __shared__ unsigned short Bl[16 * KPAD];
    __shared__ float R[64 * 16];
    int tid = threadIdx.x;
    int wv = tid >> 6, lane = tid & 63;
    int u0 = blockIdx.x * 4;
    const unsigned short* Ht = HS + (size_t)t * (BB * HH);
    f32x4 acc = {0.f, 0.f, 0.f, 0.f};
    for (int kc = 0; kc < 1536; kc += KC) {
#pragma unroll
        for (int it = 0; it < 4; ++it) {       // A: 64 rows x 16 octets
            int slot = it * 256 + tid;
            int ar = slot >> 4;
            int ak = (slot & 15) * 8;
            int k = kc + ak;
            const unsigned short* sp = (k < 1024)
                ? (Ht + (size_t)ar * HH + k)
                : (X + (size_t)(t * BB + ar) * II + (k - 1024));
            *(uint4*)&Al[ar * KPAD + ak] = *(const uint4*)sp;
        }
        {                                      // B: 16 rows x 16 octets
            int br = tid >> 4;
            int bk = (tid & 15) * 8;
            int k = kc + bk;
            int gate = br >> 2, ul = br & 3;
            int wrow = gate * HH + u0 + ul;
            const unsigned short* sp = (k < 1024)
                ? (Whh + (size_t)wrow * HH + k)
                : (Wih + (size_t)wrow * II + (k - 1024));
            *(uint4*)&Bl[br * KPAD + bk] = *(const uint4*)sp;
        }
        __syncthreads();
        int row0 = wv * 16 + (lane & 15);
        int ko0 = (lane >> 4) * 8;
#pragma unroll
        for (int ks = 0; ks < KC; ks += 32) {
            s16x8 a = *(const s16x8*)&Al[row0 * KPAD + ks + ko0];
            s16x8 bq = *(const s16x8*)&Bl[(lane & 15) * KPAD + ks + ko0];
            acc = __builtin_amdgcn_mfma_f32_16x16x32_bf16(a, bq, acc, 0, 0, 0);
        }
        __syncthreads();
    }
    // scatter D frag to LDS: rows wv*16 + (lane>>4)*4 + q, col lane&15
    int colD = lane & 15;
    int rbase = wv * 16 + (lane >> 4) * 4;
#pragma unroll
    for (int q = 0; q < 4; ++q) R[(rbase + q) * 16 + colD] = acc[q];
    __syncthreads();
    // gates: one (row, unit) per thread
    int row = tid >> 2, ul = tid & 3;
    int u = u0 + ul;
    float iv = R[row * 16 + 0 * 4 + ul] + b_ih[0 * HH + u] + b_hh[0 * HH + u];
    float fv = R[row * 16 + 1 * 4 + ul] + b_ih[1 * HH + u] + b_hh[1 * HH + u];
    float gv = R[row * 16 + 2 * 4 + ul] + b_ih[2 * HH + u] + b_hh[2 * HH + u];
    float ov = R[row * 16 + 3 * 4 + ul] + b_ih[3 * HH + u] + b_hh[3 * HH + u];
    float si = 1.f / (1.f + __expf(-iv));
    float sf = 1.f / (1.f + __expf(-fv));
    float so = 1.f / (1.f + __expf(-ov));
    float cold = C[(size_t)row * HH + u];
    float cnew = sf * cold + si * tanhf(gv);
    float h = so * tanhf(cnew);
    C[(size_t)row * HH + u] = cnew;
    HS[(size_t)(t + 1) * (BB * HH) + (size_t)row * HH + u] = f2bf(h);
}

// ---------- fused logits GEMM + partial softmax ----------
// tile 64 rows x 128 cols; 4 waves, each 64x32 (4 M-frags x 2 N-frags)
static constexpr int LKC = 64;
static constexpr int LKPAD = 72;
__global__ __launch_bounds__(256) void logits_kernel(
    const unsigned short* __restrict__ A,    // [4032][1024] = HS + 64*1024
    const unsigned short* __restrict__ Wo,   // [32000][1024]
    const float* __restrict__ b_out,
    const int* __restrict__ TGT,
    float* __restrict__ PM, float* __restrict__ PS,
    float* __restrict__ TLOG) {
    __shared__ unsigned short Al[64 * LKPAD];    // 9216 B
    __shared__ unsigned short Bl[128 * LKPAD];   // 18432 B
    int tid = threadIdx.x, wv = tid >> 6, lane = tid & 63;
    int nblk = blockIdx.x;    // 250
    int mblk = blockIdx.y;    // 63
    int rbase = mblk * 64;
    int v0 = nblk * 128;
    f32x4 acc[4][2];
#pragma unroll
    for (int mf = 0; mf < 4; ++mf)
#pragma unroll
        for (int nf = 0; nf < 2; ++nf) acc[mf][nf] = (f32x4){0.f, 0.f, 0.f, 0.f};

    for (int kc = 0; kc < 1024; kc += LKC) {
#pragma unroll
        for (int it = 0; it < 2; ++it) {          // A: 64 x 8 octets
            int slot = it * 256 + tid;
            int ar = slot >> 3, ak = (slot & 7) * 8;
            *(uint4*)&Al[ar * LKPAD + ak] =
                *(const uint4*)(A + (size_t)(rbase + ar) * HH + kc + ak);
        }
#pragma unroll
        for (int it = 0; it < 4; ++it) {          // B: 128 x 8 octets
            int slot = it * 256 + tid;
            int br = slot >> 3, bk = (slot & 7) * 8;
            *(uint4*)&Bl[br * LKPAD + bk] =
                *(const uint4*)(Wo + (size_t)(v0 + br) * HH + kc + bk);
        }
        __syncthreads();
        int ko0 = (lane >> 4) * 8;
        int rl = lane & 15;
#pragma unroll
        for (int ks = 0; ks < LKC; ks += 32) {
            int ko = ks + ko0;
            s16x8 a[4], bq[2];
#pragma unroll
            for (int mf = 0; mf < 4; ++mf)
                a[mf] = *(const s16x8*)&Al[(mf * 16 + rl) * LKPAD + ko];
#pragma unroll
            for (int nf = 0; nf < 2; ++nf)
                bq[nf] = *(const s16x8*)&Bl[(wv * 32 + nf * 16 + rl) * LKPAD + ko];
#pragma unroll
            for (int mf = 0; mf < 4; ++mf)
#pragma unroll
                for (int nf = 0; nf < 2; ++nf)
                    acc[mf][nf] = __builtin_amdgcn_mfma_f32_16x16x32_bf16(
                        a[mf], bq[nf], acc[mf][nf], 0, 0, 0);
        }
        __syncthreads();
    }
    // epilogue: bias + per-row (max, sumexp) over this wave's 32 cols
    int cbase = v0 + wv * 32;
    int cl = lane & 15;
    int lg = lane >> 4;
    float bo0 = b_out[cbase + cl];
    float bo1 = b_out[cbase + 16 + cl];
    int vb = nblk * 4 + wv;
#pragma unroll
    for (int mf = 0; mf < 4; ++mf) {
#pragma unroll
        for (int q = 0; q < 4; ++q) {
            int r = rbase + mf * 16 + lg * 4 + q;
            int tg = TGT[r];
            float e0 = acc[mf][0][q] + bo0;
            float e1 = acc[mf][1][q] + bo1;
            if (cbase + cl == tg)      TLOG[r] = e0;
            if (cbase + 16 + cl == tg) TLOG[r] = e1;
            float m = fmaxf(e0, e1);
#pragma unroll
            for (int msk = 1; msk < 16; msk <<= 1) m = fmaxf(m, __shfl_xor(m, msk));
            float s = __expf(e0 - m) + __expf(e1 - m);
#pragma unroll
            for (int msk = 1; msk < 16; msk <<= 1) s += __shfl_xor(s, msk);
            if (cl == 0) {
                PM[(size_t)r * 1024 + vb] = m;
                PS[(size_t)r * 1024 + vb] = s;
            }
        }
    }
}

// ---------- per-row reduction of 1000 partials ----------
__global__ void rowred_kernel(const float* __restrict__ PM,
                              const float* __restrict__ PS,
                              const float* __restrict__ TLOG,
                              const int* __restrict__ TGT,
                              float* __restrict__ ROWLP) {
    int r = blockIdx.x * 4 + (threadIdx.x >> 6);
    int lane = threadIdx.x & 63;
    if (r >= NR) return;
    const float* pm = PM + (size_t)r * 1024;
    const float* ps = PS + (size_t)r * 1024;
    float m = -1e30f;
    for (int vb = lane; vb < 1000; vb += 64) m = fmaxf(m, pm[vb]);
    for (int off = 32; off; off >>= 1) m = fmaxf(m, __shfl_xor(m, off));
    float s = 0.f;
    for (int vb = lane; vb < 1000; vb += 64) s += ps[vb] * __expf(pm[vb] - m);
    for (int off = 32; off; off >>= 1) s += __shfl_xor(s, off);
    if (lane == 0) {
        float lse = m + logf(s);
        float lp = TLOG[r] - lse;
        ROWLP[r] = (TGT[r] != 0) ? lp : 0.f;
    }
}

// ---------- final loss ----------
__global__ void final_kernel(const float* __restrict__ ROWLP,
                             const int* __restrict__ TGT,
                             float* __restrict__ out) {
    int tid = threadIdx.x;
    float sum = 0.f; int cnt = 0;
    for (int r = tid; r < NR; r += 256) {
        sum += ROWLP[r];
        cnt += (TGT[r] != 0);
    }
    for (int off = 32; off; off >>= 1) {
        sum += __shfl_xor(sum, off);
        cnt += __shfl_xor(cnt, off);
    }
    __shared__ float wsum[4];
    __shared__ int wcnt[4];
    if ((tid & 63) == 0) { wsum[tid >> 6] = sum; wcnt[tid >> 6] = cnt; }
    __syncthreads();
    if (tid == 0) {
        float S = wsum[0] + wsum[1] + wsum[2] + wsum[3];
        int Cc = wcnt[0] + wcnt[1] + wcnt[2] + wcnt[3];
        out[0] = -S / fmaxf((float)Cc, 1.f);
        out[1] = (float)Cc;
    }
}

extern "C" void kernel_launch(void* const* d_in, const int* in_sizes, int n_in,
                              void* d_out, int out_size, void* d_ws, size_t ws_size,
                              hipStream_t stream) {
    const float* src    = (const float*)d_in[0];
    const int*   tgtids = (const int*)d_in[1];
    const float* embed  = (const float*)d_in[2];
    const float* W_h    = (const float*)d_in[3];
    const float* b_h    = (const float*)d_in[4];
    const float* W_c    = (const float*)d_in[5];
    const float* b_c    = (const float*)d_in[6];
    const float* W_ih   = (const float*)d_in[7];
    const float* W_hh   = (const float*)d_in[8];
    const float* b_ih   = (const float*)d_in[9];
    const float* b_hh   = (const float*)d_in[10];
    const float* W_out  = (const float*)d_in[11];
    const float* b_out  = (const float*)d_in[12];
    float* out = (float*)d_out;

    char* ws = (char*)d_ws;
    size_t off = 0;
    auto alloc = [&](size_t bytes) {
        size_t cur = off;
        off += (bytes + 255) & ~(size_t)255;
        return cur;
    };
    unsigned short* Wo_bf  = (unsigned short*)(ws + alloc((size_t)VV * HH * 2));
    unsigned short* Whh_bf = (unsigned short*)(ws + alloc((size_t)4 * HH * HH * 2));
    unsigned short* Wih_bf = (unsigned short*)(ws + alloc((size_t)4 * HH * II * 2));
    unsigned short* X_bf   = (unsigned short*)(ws + alloc((size_t)NR * II * 2));
    unsigned short* HS     = (unsigned short*)(ws + alloc((size_t)64 * BB * HH * 2));
    float* Cst   = (float*)(ws + alloc((size_t)BB * HH * 4));
    float* PM    = (float*)(ws + alloc((size_t)NR * 1024 * 4));
    float* PS    = (float*)(ws + alloc((size_t)NR * 1024 * 4));
    float* TLOG  = (float*)(ws + alloc((size_t)NR * 4));
    int*   TGT   = (int*)(ws + alloc((size_t)NR * 4));
    float* ROWLP = (float*)(ws + alloc((size_t)NR * 4));

    cvt_kernel<<<4096, 256, 0, stream>>>(W_out, Wo_bf, VV * HH / 4);
    cvt_kernel<<<1024, 256, 0, stream>>>(W_hh, Whh_bf, 4 * HH * HH / 4);
    cvt_kernel<<<512, 256, 0, stream>>>(W_ih, Wih_bf, 4 * HH * II / 4);
    gather_kernel<<<(NR * (II / 4) + 255) / 256, 256, 0, stream>>>(embed, tgtids, X_bf, TGT);
    init_hc_kernel<<<4096, 256, 0, stream>>>(src, W_h, b_h, W_c, b_c, HS, Cst);
    for (int t = 0; t < NT; ++t) {
        lstm_step_kernel<<<256, 256, 0, stream>>>(HS, X_bf, Whh_bf, Wih_bf,
                                                  b_ih, b_hh, Cst, t);
    }
    logits_kernel<<<dim3(VV / 128, NR / 64), 256, 0, stream>>>(
        HS + (size_t)BB * HH, Wo_bf, b_out, TGT, PM, PS, TLOG);
    rowred_kernel<<<NR / 4, 256, 0, stream>>>(PM, PS, TLOG, TGT, ROWLP);
    final_kernel<<<1, 256, 0, stream>>>(ROWLP, TGT, out);
}

// Round 2
// 1037.848 us; speedup vs baseline: 1.2841x; 1.2841x over previous
//
#include <hip/hip_runtime.h>
#include <math.h>

static constexpr int BB = 64;      // batch
static constexpr int TT = 64;      // tgt seq len
static constexpr int VV = 32000;   // vocab
static constexpr int II = 512;     // embed dim
static constexpr int HH = 1024;    // hidden
static constexpr int GG = 2048;    // img dim
static constexpr int NT = 63;      // LSTM steps
static constexpr int NR = NT * BB; // 4032 output rows
static constexpr int MP = 4096;    // padded M
static constexpr int NVB = 500;    // 64-col vocab blocks per row
static constexpr int VBS = 512;    // PM/PS row stride

using s16x8 = __attribute__((ext_vector_type(8))) short;
using f32x4 = __attribute__((ext_vector_type(4))) float;

__device__ __forceinline__ unsigned short f2bf(float f) {
    union { float f; unsigned u; } v; v.f = f;
    unsigned r = v.u + 0x7FFFu + ((v.u >> 16) & 1u);
    return (unsigned short)(r >> 16);
}
__device__ __forceinline__ float bf2f(unsigned short h) {
    union { unsigned u; float f; } v; v.u = ((unsigned)h) << 16;
    return v.f;
}

__device__ __forceinline__ void gload_lds16(const unsigned short* g,
                                            unsigned short* l) {
    __builtin_amdgcn_global_load_lds(
        (const __attribute__((address_space(1))) void*)g,
        (__attribute__((address_space(3))) void*)l, 16, 0, 0);
}

// ---------- f32 -> bf16 convert ----------
__global__ void cvt_kernel(const float* __restrict__ in,
                           unsigned short* __restrict__ out, int n4) {
    int idx = blockIdx.x * blockDim.x + threadIdx.x;
    int stride = gridDim.x * blockDim.x;
    for (int i = idx; i < n4; i += stride) {
        float4 v = ((const float4*)in)[i];
        ushort4 o;
        o.x = f2bf(v.x); o.y = f2bf(v.y); o.z = f2bf(v.z); o.w = f2bf(v.w);
        ((ushort4*)out)[i] = o;
    }
}

// ---------- embedding gather (+ target ids) ----------
__global__ void gather_kernel(const float* __restrict__ embed,
                              const int* __restrict__ tgt_ids,
                              unsigned short* __restrict__ X,
                              int* __restrict__ TGT) {
    int idx = blockIdx.x * 256 + threadIdx.x;   // over NR * II/4
    if (idx >= NR * (II / 4)) return;
    int r = idx / (II / 4);
    int kq = idx % (II / 4);
    int t = r / BB, b = r % BB;
    int tok = tgt_ids[b * TT + t];
    float4 v = ((const float4*)(embed + (size_t)tok * II))[kq];
    ushort4 o;
    o.x = f2bf(v.x); o.y = f2bf(v.y); o.z = f2bf(v.z); o.w = f2bf(v.w);
    ((ushort4*)(X + (size_t)r * II))[kq] = o;
    if (kq == 0) TGT[r] = tgt_ids[b * TT + t + 1];
}

// ---------- h0/c0 init ----------
__global__ __launch_bounds__(256) void init_hc_kernel(
    const float* __restrict__ src,
    const float* __restrict__ W_h, const float* __restrict__ b_h,
    const float* __restrict__ W_c, const float* __restrict__ b_c,
    unsigned short* __restrict__ HS, float* __restrict__ C) {
    int wave = blockIdx.x * 4 + (threadIdx.x >> 6);
    int lane = threadIdx.x & 63;
    int sel = wave >> 13;          // 0 = h, 1 = c
    int rem = wave & 8191;
    int j = rem >> 3;
    int b0 = (rem & 7) * 8;
    const float* w = (sel ? W_c : W_h) + (size_t)j * GG;
    float acc[8] = {0.f,0.f,0.f,0.f,0.f,0.f,0.f,0.f};
    for (int k = lane; k < GG; k += 64) {
        float wv = w[k];
#pragma unroll
        for (int bb = 0; bb < 8; ++bb)
            acc[bb] += wv * src[(size_t)(b0 + bb) * GG + k];
    }
#pragma unroll
    for (int bb = 0; bb < 8; ++bb)
        for (int off = 32; off; off >>= 1)
            acc[bb] += __shfl_xor(acc[bb], off);
    if (lane == 0) {
        float bias = sel ? b_c[j] : b_h[j];
#pragma unroll
        for (int bb = 0; bb < 8; ++bb) {
            float v = tanhf(acc[bb] + bias);
            if (sel == 0) HS[(size_t)(b0 + bb) * HH + j] = f2bf(v);
            else          C[(size_t)(b0 + bb) * HH + j] = v;
        }
    }
}

// ---------- shared 128x128 GEMM body (m97 structure) ----------
// A: [.., KTOT] row-major bf16, rbase applied by caller
// B: [.., KTOT] row-major bf16 (output cols = B rows), v0 applied by caller
// LDS: Al/Bl each 128x64 bf16 linear (global_load_lds dest)
template<int KTOT>
__device__ __forceinline__ void gemm_body(
    const unsigned short* __restrict__ Abase,
    const unsigned short* __restrict__ Bbase,
    unsigned short* Al, unsigned short* Bl,
    int tid, f32x4 (&acc)[4][4]) {
    int wv = tid >> 6, lane = tid & 63;
    int rl = lane & 15, ko0 = (lane >> 4) * 8;
    int wr = wv >> 1, wc = wv & 1;
    for (int kc = 0; kc < KTOT; kc += 64) {
        if (kc) __syncthreads();          // previous compute done
#pragma unroll
        for (int it = 0; it < 4; ++it) {  // 4x(256 lanes x 16B) per operand
            int c = it * 256 + tid;
            int row = c >> 3, k8 = (c & 7) * 8;
            unsigned short* ldsw = (unsigned short*)((it * 256 + wv * 64) * 8);
            gload_lds16(Abase + (size_t)row * KTOT + kc + k8,
                        Al + (size_t)(it * 256 + wv * 64) * 8);
            gload_lds16(Bbase + (size_t)row * KTOT + kc + k8,
                        Bl + (size_t)(it * 256 + wv * 64) * 8);
            (void)ldsw;
        }
        __syncthreads();                  // loads landed (vmcnt drained)
        const unsigned short* Ab = Al + (wr * 64 + rl) * 64 + ko0;
        const unsigned short* Bb = Bl + (wc * 64 + rl) * 64 + ko0;
#pragma unroll
        for (int ks = 0; ks < 2; ++ks) {
            s16x8 a[4], b[4];
#pragma unroll
            for (int mf = 0; mf < 4; ++mf)
                a[mf] = *(const s16x8*)(Ab + mf * 16 * 64 + ks * 32);
#pragma unroll
            for (int nf = 0; nf < 4; ++nf)
                b[nf] = *(const s16x8*)(Bb + nf * 16 * 64 + ks * 32);
#pragma unroll
            for (int mf = 0; mf < 4; ++mf)
#pragma unroll
                for (int nf = 0; nf < 4; ++nf)
                    acc[mf][nf] = __builtin_amdgcn_mfma_f32_16x16x32_bf16(
                        a[mf], b[nf], acc[mf][nf], 0, 0, 0);
        }
    }
}

// ---------- Gx = X @ W_ih^T + b_ih + b_hh (bf16 out) ----------
__global__ __launch_bounds__(256) void gx_kernel(
    const unsigned short* __restrict__ X,     // [4096][512]
    const unsigned short* __restrict__ Wih,   // [4096][512]
    const float* __restrict__ b_ih, const float* __restrict__ b_hh,
    unsigned short* __restrict__ Gx) {        // [4096][4096]
    __shared__ unsigned short Al[128 * 64];
    __shared__ unsigned short Bl[128 * 64];
    int tid = threadIdx.x;
    int mblk = blockIdx.x, nblk = blockIdx.y;
    int rbase = mblk * 128, v0 = nblk * 128;
    f32x4 acc[4][4];
#pragma unroll
    for (int mf = 0; mf < 4; ++mf)
#pragma unroll
        for (int nf = 0; nf < 4; ++nf) acc[mf][nf] = (f32x4){0.f,0.f,0.f,0.f};
    gemm_body<II>(X + (size_t)rbase * II, Wih + (size_t)v0 * II, Al, Bl, tid, acc);
    int wv = tid >> 6, lane = tid & 63;
    int rl = lane & 15, lg = lane >> 4;
    int wr = wv >> 1, wc = wv & 1;
    float bsum[4];
#pragma unroll
    for (int nf = 0; nf < 4; ++nf) {
        int col = v0 + wc * 64 + nf * 16 + rl;
        bsum[nf] = b_ih[col] + b_hh[col];
    }
#pragma unroll
    for (int mf = 0; mf < 4; ++mf)
#pragma unroll
        for (int q = 0; q < 4; ++q) {
            int r = rbase + wr * 64 + mf * 16 + lg * 4 + q;
#pragma unroll
            for (int nf = 0; nf < 4; ++nf) {
                int col = v0 + wc * 64 + nf * 16 + rl;
                Gx[(size_t)r * 4096 + col] = f2bf(acc[mf][nf][q] + bsum[nf]);
            }
        }
}

// ---------- LSTM step: h @ W_hh^T (K=1024) + Gx + gates ----------
// 256 blocks; block handles 4 hidden units (16 cols = 4 gates x 4 units)
static constexpr int KP = 1032;   // padded LDS row stride (bf16)
__global__ __launch_bounds__(256) void lstm_step_kernel(
    unsigned short* __restrict__ HS,          // [64 slots][64][1024]
    const unsigned short* __restrict__ Gx,    // [4096][4096]
    const unsigned short* __restrict__ Whh,   // [4096][1024]
    float* __restrict__ C, int t) {
    __shared__ unsigned short Bs[16 * KP];    // 33 KB
    __shared__ float R[64 * 16];
    int tid = threadIdx.x;
    int wv = tid >> 6, lane = tid & 63;
    int rl = lane & 15, lg = lane >> 4;
    int u0 = blockIdx.x * 4;
    const unsigned short* h = HS + (size_t)t * (BB * HH);
    // stage this block's 16 W_hh rows into LDS (padded stride, once)
#pragma unroll
    for (int it = 0; it < 8; ++it) {
        int c = it * 256 + tid;               // 16B chunk index
        int br = c >> 7, k8 = (c & 127) * 8;
        int wrow = (br >> 2) * HH + u0 + (br & 3);
        *(uint4*)&Bs[br * KP + k8] = *(const uint4*)(Whh + (size_t)wrow * HH + k8);
    }
    __syncthreads();
    const unsigned short* Ab = h + (size_t)(wv * 16 + rl) * HH;
    const unsigned short* Bb = Bs + rl * KP;
    f32x4 acc0 = {0.f,0.f,0.f,0.f}, acc1 = {0.f,0.f,0.f,0.f};
#pragma unroll
    for (int kc = 0; kc < HH; kc += 64) {
        int k0 = kc + lg * 8;
        s16x8 a0 = *(const s16x8*)(Ab + k0);
        s16x8 b0 = *(const s16x8*)(Bb + k0);
        acc0 = __builtin_amdgcn_mfma_f32_16x16x32_bf16(a0, b0, acc0, 0, 0, 0);
        s16x8 a1 = *(const s16x8*)(Ab + k0 + 32);
        s16x8 b1 = *(const s16x8*)(Bb + k0 + 32);
        acc1 = __builtin_amdgcn_mfma_f32_16x16x32_bf16(a1, b1, acc1, 0, 0, 0);
    }
    f32x4 acc = acc0 + acc1;
    // scatter D frag: row = wv*16 + lg*4 + q, col = rl
#pragma unroll
    for (int q = 0; q < 4; ++q) R[(wv * 16 + lg * 4 + q) * 16 + rl] = acc[q];
    __syncthreads();
    // gates: one (row, unit) per thread
    int row = tid >> 2, ul = tid & 3;
    int u = u0 + ul;
    const unsigned short* gx = Gx + (size_t)(t * BB + row) * 4096;
    float iv = R[row * 16 + 0 * 4 + ul] + bf2f(gx[0 * HH + u]);
    float fv = R[row * 16 + 1 * 4 + ul] + bf2f(gx[1 * HH + u]);
    float gv = R[row * 16 + 2 * 4 + ul] + bf2f(gx[2 * HH + u]);
    float ov = R[row * 16 + 3 * 4 + ul] + bf2f(gx[3 * HH + u]);
    float si = 1.f / (1.f + __expf(-iv));
    float sf = 1.f / (1.f + __expf(-fv));
    float so = 1.f / (1.f + __expf(-ov));
    float cold = C[(size_t)row * HH + u];
    float cnew = sf * cold + si * tanhf(gv);
    float hv = so * tanhf(cnew);
    C[(size_t)row * HH + u] = cnew;
    HS[(size_t)(t + 1) * (BB * HH) + (size_t)row * HH + u] = f2bf(hv);
}

// ---------- fused logits GEMM (128x128) + partial softmax ----------
__global__ __launch_bounds__(256) void logits_kernel(
    const unsigned short* __restrict__ A,    // [4096][1024] (HS + 64*1024)
    const unsigned short* __restrict__ Wo,   // [32000][1024]
    const float* __restrict__ b_out,
    const int* __restrict__ TGT,
    float* __restrict__ PM, float* __restrict__ PS,
    float* __restrict__ TLOG) {
    __shared__ unsigned short Al[128 * 64];
    __shared__ unsigned short Bl[128 * 64];
    int tid = threadIdx.x;
    int mblk = blockIdx.x, nblk = blockIdx.y;   // x fastest => B-panel shared
    int rbase = mblk * 128, v0 = nblk * 128;
    f32x4 acc[4][4];
#pragma unroll
    for (int mf = 0; mf < 4; ++mf)
#pragma unroll
        for (int nf = 0; nf < 4; ++nf) acc[mf][nf] = (f32x4){0.f,0.f,0.f,0.f};
    gemm_body<HH>(A + (size_t)rbase * HH, Wo + (size_t)v0 * HH, Al, Bl, tid, acc);
    // epilogue: per-row (max, sumexp) over this wave's 64 cols
    int wv = tid >> 6, lane = tid & 63;
    int rl = lane & 15, lg = lane >> 4;
    int wr = wv >> 1, wc = wv & 1;
    int cb = v0 + wc * 64;
    float bo[4];
#pragma unroll
    for (int nf = 0; nf < 4; ++nf) bo[nf] = b_out[cb + nf * 16 + rl];
    int vb = nblk * 2 + wc;
#pragma unroll
    for (int mf = 0; mf < 4; ++mf) {
        int rb = rbase + wr * 64 + mf * 16 + lg * 4;
#pragma unroll
        for (int q = 0; q < 4; ++q) {
            int r = rb + q;
            int tg = TGT[r];
            float e[4];
            float m = -1e30f;
#pragma unroll
            for (int nf = 0; nf < 4; ++nf) {
                e[nf] = acc[mf][nf][q] + bo[nf];
                if (cb + nf * 16 + rl == tg) TLOG[r] = e[nf];
                m = fmaxf(m, e[nf]);
            }
#pragma unroll
            for (int msk = 1; msk < 16; msk <<= 1) m = fmaxf(m, __shfl_xor(m, msk));
            float s = 0.f;
#pragma unroll
            for (int nf = 0; nf < 4; ++nf) s += __expf(e[nf] - m);
#pragma unroll
            for (int msk = 1; msk < 16; msk <<= 1) s += __shfl_xor(s, msk);
            if (rl == 0) {
                PM[(size_t)r * VBS + vb] = m;
                PS[(size_t)r * VBS + vb] = s;
            }
        }
    }
}

// ---------- per-row reduction of 500 partials ----------
__global__ void rowred_kernel(const float* __restrict__ PM,
                              const float* __restrict__ PS,
                              const float* __restrict__ TLOG,
                              const int* __restrict__ TGT,
                              float* __restrict__ ROWLP) {
    int r = blockIdx.x * 4 + (threadIdx.x >> 6);
    int lane = threadIdx.x & 63;
    if (r >= NR) return;
    const float* pm = PM + (size_t)r * VBS;
    const float* ps = PS + (size_t)r * VBS;
    float m = -1e30f;
    for (int vb = lane; vb < NVB; vb += 64) m = fmaxf(m, pm[vb]);
    for (int off = 32; off; off >>= 1) m = fmaxf(m, __shfl_xor(m, off));
    float s = 0.f;
    for (int vb = lane; vb < NVB; vb += 64) s += ps[vb] * __expf(pm[vb] - m);
    for (int off = 32; off; off >>= 1) s += __shfl_xor(s, off);
    if (lane == 0) {
        float lse = m + logf(s);
        float lp = TLOG[r] - lse;
        ROWLP[r] = (TGT[r] != 0) ? lp : 0.f;
    }
}

// ---------- final loss ----------
__global__ void final_kernel(const float* __restrict__ ROWLP,
                             const int* __restrict__ TGT,
                             float* __restrict__ out) {
    int tid = threadIdx.x;
    float sum = 0.f; int cnt = 0;
    for (int r = tid; r < NR; r += 256) {
        sum += ROWLP[r];
        cnt += (TGT[r] != 0);
    }
    for (int off = 32; off; off >>= 1) {
        sum += __shfl_xor(sum, off);
        cnt += __shfl_xor(cnt, off);
    }
    __shared__ float wsum[4];
    __shared__ int wcnt[4];
    if ((tid & 63) == 0) { wsum[tid >> 6] = sum; wcnt[tid >> 6] = cnt; }
    __syncthreads();
    if (tid == 0) {
        float S = wsum[0] + wsum[1] + wsum[2] + wsum[3];
        int Cc = wcnt[0] + wcnt[1] + wcnt[2] + wcnt[3];
        out[0] = -S / fmaxf((float)Cc, 1.f);
        out[1] = (float)Cc;
    }
}

extern "C" void kernel_launch(void* const* d_in, const int* in_sizes, int n_in,
                              void* d_out, int out_size, void* d_ws, size_t ws_size,
                              hipStream_t stream) {
    const float* src    = (const float*)d_in[0];
    const int*   tgtids = (const int*)d_in[1];
    const float* embed  = (const float*)d_in[2];
    const float* W_h    = (const float*)d_in[3];
    const float* b_h    = (const float*)d_in[4];
    const float* W_c    = (const float*)d_in[5];
    const float* b_c    = (const float*)d_in[6];
    const float* W_ih   = (const float*)d_in[7];
    const float* W_hh   = (const float*)d_in[8];
    const float* b_ih   = (const float*)d_in[9];
    const float* b_hh   = (const float*)d_in[10];
    const float* W_out  = (const float*)d_in[11];
    const float* b_out  = (const float*)d_in[12];
    float* out = (float*)d_out;

    char* ws = (char*)d_ws;
    size_t off = 0;
    auto alloc = [&](size_t bytes) {
        size_t cur = off;
        off += (bytes + 255) & ~(size_t)255;
        return cur;
    };
    unsigned short* Wo_bf  = (unsigned short*)(ws + alloc((size_t)VV * HH * 2));
    unsigned short* Whh_bf = (unsigned short*)(ws + alloc((size_t)4 * HH * HH * 2));
    unsigned short* Wih_bf = (unsigned short*)(ws + alloc((size_t)4 * HH * II * 2));
    unsigned short* X_bf   = (unsigned short*)(ws + alloc((size_t)MP * II * 2));
    unsigned short* HS     = (unsigned short*)(ws + alloc((size_t)64 * BB * HH * 2));
    float* Cst   = (float*)(ws + alloc((size_t)BB * HH * 4));
    unsigned short* Gx = (unsigned short*)(ws + alloc((size_t)MP * 4096 * 2));
    float* PM    = (float*)(ws + alloc((size_t)MP * VBS * 4));
    float* PS    = (float*)(ws + alloc((size_t)MP * VBS * 4));
    float* TLOG  = (float*)(ws + alloc((size_t)MP * 4));
    int*   TGT   = (int*)(ws + alloc((size_t)MP * 4));
    float* ROWLP = (float*)(ws + alloc((size_t)NR * 4));

    cvt_kernel<<<4096, 256, 0, stream>>>(W_out, Wo_bf, VV * HH / 4);
    cvt_kernel<<<1024, 256, 0, stream>>>(W_hh, Whh_bf, 4 * HH * HH / 4);
    cvt_kernel<<<512, 256, 0, stream>>>(W_ih, Wih_bf, 4 * HH * II / 4);
    gather_kernel<<<(NR * (II / 4) + 255) / 256, 256, 0, stream>>>(embed, tgtids, X_bf, TGT);
    init_hc_kernel<<<4096, 256, 0, stream>>>(src, W_h, b_h, W_c, b_c, HS, Cst);
    gx_kernel<<<dim3(MP / 128, 4096 / 128), 256, 0, stream>>>(
        X_bf, Wih_bf, b_ih, b_hh, Gx);
    for (int t = 0; t < NT; ++t) {
        lstm_step_kernel<<<256, 256, 0, stream>>>(HS, Gx, Whh_bf, Cst, t);
    }
    logits_kernel<<<dim3(MP / 128, VV / 128), 256, 0, stream>>>(
        HS + (size_t)BB * HH, Wo_bf, b_out, TGT, PM, PS, TLOG);
    rowred_kernel<<<NR / 4, 256, 0, stream>>>(PM, PS, TLOG, TGT, ROWLP);
    final_kernel<<<1, 256, 0, stream>>>(ROWLP, TGT, out);
}